// Round 9
// baseline (408.272 us; speedup 1.0000x reference)
//
#include <hip/hip_runtime.h>
#include <math.h>

#define D 128

typedef short s8v __attribute__((ext_vector_type(8)));
typedef float f32x4 __attribute__((ext_vector_type(4)));
typedef unsigned short u16x8 __attribute__((ext_vector_type(8)));

__device__ __forceinline__ unsigned short f2bf(float f) {
  union { float f; unsigned u; } c; c.f = f;
  unsigned u = c.u;
  unsigned r = (u + 0x7fffu + ((u >> 16) & 1u)) >> 16;
  return (unsigned short)r;
}

__device__ __forceinline__ void gload_lds16(const void* g, void* l) {
  __builtin_amdgcn_global_load_lds((const __attribute__((address_space(1))) void*)g,
                                   (__attribute__((address_space(3))) void*)l, 16, 0, 0);
}

// slab layout for intermediate bf16 feature buffers:
//   element (node, c) stored at  (c>>4)*n*16 + node*16 + (c&15)
// slab = 16 columns = 32 B/node; one slab = n*32 B (3.2 MB) -> fits one XCD L2.

// ---------------- prep: weight cvt (blocks 0..127) + bucket count (rest) ----------------
__global__ __launch_bounds__(256) void k_prep(const float* __restrict__ Wp,
                                              const float* __restrict__ Wl,
                                              const float* __restrict__ Wr,
                                              const float* __restrict__ Wlo,
                                              const float* __restrict__ Wro,
                                              unsigned short* __restrict__ Wb,
                                              const int* __restrict__ dst,
                                              int* __restrict__ bucketCnt, int E_) {
  int t = threadIdx.x;
  if (blockIdx.x < 128) {
    int i = blockIdx.x * 256 + t;  // float4 units, 0..32767
    const float* s;
    int off;
    if (i < 8192)       { s = Wp;  off = 0; }
    else if (i < 16384) { s = Wl;  off = 8192; }
    else if (i < 24576) { s = Wr;  off = 16384; }
    else if (i < 28672) { s = Wlo; off = 24576; }
    else                { s = Wro; off = 28672; }
    float4 a = ((const float4*)s)[i - off];
    ushort4 o;
    o.x = f2bf(a.x); o.y = f2bf(a.y); o.z = f2bf(a.z); o.w = f2bf(a.w);
    ((ushort4*)Wb)[i] = o;
  } else {
    __shared__ int hist[512];
    hist[t] = 0; hist[t + 256] = 0;
    __syncthreads();
    int base = (blockIdx.x - 128) * 4096;
#pragma unroll
    for (int i = 0; i < 16; i++) {
      int e = base + i * 256 + t;
      if (e < E_) atomicAdd(&hist[dst[e] >> 8], 1);
    }
    __syncthreads();
    int c = hist[t];       if (c) atomicAdd(&bucketCnt[t], c);
    c = hist[t + 256];     if (c) atomicAdd(&bucketCnt[t + 256], c);
  }
}

// single block: exclusive scan of 512 bucket counts
__global__ __launch_bounds__(512) void k_bucket_scan(const int* __restrict__ cnt,
                                                     int* __restrict__ base,
                                                     int* __restrict__ cursor,
                                                     int* __restrict__ row_start,
                                                     int n, int E_) {
  __shared__ int bs[512];
  int t = threadIdx.x;
  int orig = cnt[t];
  bs[t] = orig;
  __syncthreads();
  for (int off = 1; off < 512; off <<= 1) {
    int x = (t >= off) ? bs[t - off] : 0;
    __syncthreads();
    bs[t] += x;
    __syncthreads();
  }
  int ex = bs[t] - orig;
  base[t] = ex;
  cursor[t] = ex;
  if (t == 511) base[512] = bs[511];
  if (t == 0) row_start[n] = E_;   // sentinel
}

// Pass A: bin packed (src<<8|dst&255) into bucket regions. 16384 edges / block.
__global__ __launch_bounds__(1024) void k_partA(const int* __restrict__ src,
                                                const int* __restrict__ dst,
                                                int* __restrict__ cursor,
                                                unsigned* __restrict__ pairs, int E_) {
  __shared__ int hist[512];
  __shared__ int gbase[512];
  int t = threadIdx.x;
  int base = blockIdx.x * 16384;
  if (t < 512) hist[t] = 0;
  __syncthreads();
  unsigned p_[16];
  int k_[16];
#pragma unroll
  for (int i = 0; i < 16; i++) {
    int e = base + i * 1024 + t;
    if (e < E_) {
      int s = src[e], d = dst[e];
      p_[i] = ((unsigned)s << 8) | (unsigned)(d & 255);
      k_[i] = d >> 8;
      atomicAdd(&hist[k_[i]], 1);
    } else {
      k_[i] = -1;
    }
  }
  __syncthreads();
  if (t < 512) {
    int c = hist[t];
    gbase[t] = c ? atomicAdd(&cursor[t], c) : 0;
    hist[t] = 0;
  }
  __syncthreads();
#pragma unroll
  for (int i = 0; i < 16; i++) {
    if (k_[i] >= 0) {
      int r = atomicAdd(&hist[k_[i]], 1);
      pairs[gbase[k_[i]] + r] = p_[i];
    }
  }
}

// Pass B: one block per bucket; LDS hist -> scan -> row_start + csr fill.
__global__ __launch_bounds__(256) void k_partB(const unsigned* __restrict__ pairs,
                                               const int* __restrict__ bucketBase,
                                               int* __restrict__ row_start,
                                               int* __restrict__ csr, int n) {
  __shared__ int cnt[256];
  __shared__ int scn[256];
  int k = blockIdx.x, t = threadIdx.x;
  int node0 = k << 8;
  int pbeg = bucketBase[k], pend = bucketBase[k + 1];
  cnt[t] = 0;
  __syncthreads();
  for (int p = pbeg + t; p < pend; p += 256) atomicAdd(&cnt[pairs[p] & 255], 1);
  __syncthreads();
  int c = cnt[t];
  scn[t] = c;
  __syncthreads();
  for (int off = 1; off < 256; off <<= 1) {
    int x = (t >= off) ? scn[t - off] : 0;
    __syncthreads();
    scn[t] += x;
    __syncthreads();
  }
  int ex = scn[t] - c;
  int node = node0 + t;
  if (node < n) row_start[node] = pbeg + ex;
  __syncthreads();
  cnt[t] = pbeg + ex;   // running cursor per node
  __syncthreads();
  for (int p = pbeg + t; p < pend; p += 256) {
    unsigned pr = pairs[p];
    int slot = atomicAdd(&cnt[pr & 255], 1);
    csr[slot] = (int)(pr >> 8);
  }
}

// ---------------- mean aggregation: column-sliced, XCD-pinned ----------------
// blockIdx = chunk*8 + s. All blocks of slice s gather only from slab s
// (n*32 B = 3.2 MB), which stays resident in that XCD's L2 (round-robin
// dispatch: XCD = blockIdx % 8). 2 lanes per node, 16 B per edge per lane,
// 4-deep in-flight pipeline with 1-ahead index prefetch.
__global__ __launch_bounds__(256) void k_aggregate(const unsigned short* __restrict__ h,
                                                   unsigned short* __restrict__ agg,
                                                   const int* __restrict__ row_start,
                                                   const int* __restrict__ csr, int n) {
  int s = blockIdx.x & 7;
  int chunk = blockIdx.x >> 3;
  int t = threadIdx.x;
  int node = chunk * 128 + (t >> 1);
  int li = t & 1;
  if (node >= n) return;
  size_t n16 = (size_t)n * 16;
  int rs0 = row_start[node];
  int dc = row_start[node + 1] - rs0;
  const int* ce = csr + rs0;
  const char* base = (const char*)(h + (size_t)s * n16) + li * 16;  // + src*32

  float acc[8];
#pragma unroll
  for (int q = 0; q < 8; q++) acc[q] = 0.f;

#define ACCR(v)                                                        \
  {                                                                    \
    unsigned dw[4] = {(v).x, (v).y, (v).z, (v).w};                     \
    _Pragma("unroll") for (int q = 0; q < 4; q++) {                    \
      acc[2 * q] += __uint_as_float(dw[q] << 16);                      \
      acc[2 * q + 1] += __uint_as_float(dw[q] & 0xffff0000u);          \
    }                                                                  \
  }

  int e = 0;
  bool more = (3 < dc);
  int s0 = 0, s1 = 0, s2 = 0, s3 = 0;
  if (more) { s0 = ce[0]; s1 = ce[1]; s2 = ce[2]; s3 = ce[3]; }
  while (more) {
    uint4 v0 = *(const uint4*)(base + (size_t)s0 * 32);
    uint4 v1 = *(const uint4*)(base + (size_t)s1 * 32);
    uint4 v2 = *(const uint4*)(base + (size_t)s2 * 32);
    uint4 v3 = *(const uint4*)(base + (size_t)s3 * 32);
    e += 4;
    more = (e + 3 < dc);
    if (more) { s0 = ce[e]; s1 = ce[e + 1]; s2 = ce[e + 2]; s3 = ce[e + 3]; }
    ACCR(v0); ACCR(v1); ACCR(v2); ACCR(v3);
  }
  if (e < dc)     { uint4 v = *(const uint4*)(base + (size_t)ce[e] * 32);     ACCR(v); }
  if (e + 1 < dc) { uint4 v = *(const uint4*)(base + (size_t)ce[e + 1] * 32); ACCR(v); }
  if (e + 2 < dc) { uint4 v = *(const uint4*)(base + (size_t)ce[e + 2] * 32); ACCR(v); }
#undef ACCR

  float iv = 1.0f / (float)(dc > 0 ? dc : 1);
  u16x8 o;
#pragma unroll
  for (int q = 0; q < 8; q++) o[q] = f2bf(acc[q] * iv);
  *(u16x8*)(agg + (size_t)s * n16 + (size_t)node * 16 + li * 8) = o;
}

// LDS fragment address: logical (row r, chunk c) stored at chunk (r*16 + (c ^ (r&7)))
__device__ __forceinline__ int swz_chunk(int r, int c) { return (r << 4) + (c ^ (r & 7)); }

// ---------------- projection GEMM (async LDS-staged W): relu(A @ W^T + b) -> bf16 slab --
// 512 thr = 8 waves, 128 rows/block. CVT=1: A fp32 row-major, also writes bf16 A
// (slab layout) to xb_out. CVT=0: A bf16 slab layout. Output h: slab layout.
template <int CVT>
__global__ __launch_bounds__(512, 4) void k_gemm_proj(const void* __restrict__ Av,
                                                      const unsigned short* __restrict__ W,
                                                      const float* __restrict__ bias,
                                                      unsigned short* __restrict__ out,
                                                      unsigned short* __restrict__ xb_out,
                                                      int n) {
  __shared__ __align__(16) unsigned short Wlds[128 * 128];
  int t = threadIdx.x;
  int wv = t >> 6, l = t & 63, lg = l >> 4, ln = l & 15;
  int rb = blockIdx.x * 128 + wv * 16;
  int arow = rb + ln;
  if (arow >= n) arow = n - 1;
  size_t n16 = (size_t)n * 16;

  s8v a[4];
  if (CVT) {
    const float* Af = (const float*)Av + (size_t)arow * D + lg * 8;
#pragma unroll
    for (int ks = 0; ks < 4; ++ks) {
      float4 f0 = *(const float4*)(Af + ks * 32);
      float4 f1 = *(const float4*)(Af + ks * 32 + 4);
      s8v av;
      av[0] = (short)f2bf(f0.x); av[1] = (short)f2bf(f0.y);
      av[2] = (short)f2bf(f0.z); av[3] = (short)f2bf(f0.w);
      av[4] = (short)f2bf(f1.x); av[5] = (short)f2bf(f1.y);
      av[6] = (short)f2bf(f1.z); av[7] = (short)f2bf(f1.w);
      a[ks] = av;
      if (xb_out) {
        int c0 = ks * 32 + lg * 8;
        *(s8v*)(xb_out + (size_t)(c0 >> 4) * n16 + (size_t)arow * 16 + (c0 & 15)) = av;
      }
    }
  } else {
    const unsigned short* Ab = (const unsigned short*)Av;
#pragma unroll
    for (int ks = 0; ks < 4; ++ks) {
      int c0 = ks * 32 + lg * 8;
      a[ks] = *(const s8v*)(Ab + (size_t)(c0 >> 4) * n16 + (size_t)arow * 16 + (c0 & 15));
    }
  }

  // async global->LDS staging, pre-swizzled global source, linear LDS dest
#pragma unroll
  for (int i = 0; i < 4; ++i) {
    int idx = t + i * 512;          // chunk 0..2047
    int r = idx >> 4, k = idx & 15;
    int c = k ^ (r & 7);
    gload_lds16(W + r * 128 + c * 8, &Wlds[idx * 8]);
  }
  __syncthreads();

  f32x4 acc[8];
#pragma unroll
  for (int f = 0; f < 8; ++f) acc[f] = (f32x4){0.f, 0.f, 0.f, 0.f};
#pragma unroll
  for (int ks = 0; ks < 4; ++ks) {
#pragma unroll
    for (int f = 0; f < 8; ++f) {
      s8v b = *(const s8v*)&Wlds[swz_chunk(f * 16 + ln, ks * 4 + lg) * 8];
      acc[f] = __builtin_amdgcn_mfma_f32_16x16x32_bf16(a[ks], b, acc[f], 0, 0, 0);
    }
  }

#pragma unroll
  for (int r = 0; r < 4; ++r) {
    int gr = rb + 4 * lg + r;
    if (gr < n) {
#pragma unroll
      for (int f = 0; f < 8; ++f) {
        float v = acc[f][r] + bias[f * 16 + ln];
        v = fmaxf(v, 0.f);
        out[(size_t)f * n16 + (size_t)gr * 16 + ln] = f2bf(v);
      }
    }
  }
}

// ---------------- dual GEMM (async LDS-staged W1+W2): A1@W1^T + b + A2@W2^T ----------
// A1, A2: bf16 slab layout. MODE 0: L2-normalize rows then relu, store bf16 slab.
// MODE 1: store fp32 row-major (final output).
template <int MODE>
__global__ __launch_bounds__(512, 4) void k_gemm_dual(const unsigned short* __restrict__ A1,
                                                      const unsigned short* __restrict__ W1,
                                                      const float* __restrict__ bias,
                                                      const unsigned short* __restrict__ A2,
                                                      const unsigned short* __restrict__ W2,
                                                      void* __restrict__ outv, int n) {
  __shared__ __align__(16) unsigned short Wlds[2 * 128 * 128];
  int t = threadIdx.x;
  int wv = t >> 6, l = t & 63, lg = l >> 4, ln = l & 15;
  int rb = blockIdx.x * 128 + wv * 16;
  int arow = rb + ln;
  if (arow >= n) arow = n - 1;
  size_t n16 = (size_t)n * 16;
  s8v a1[4], a2[4];
#pragma unroll
  for (int ks = 0; ks < 4; ++ks) {
    int c0 = ks * 32 + lg * 8;
    size_t off = (size_t)(c0 >> 4) * n16 + (size_t)arow * 16 + (c0 & 15);
    a1[ks] = *(const s8v*)(A1 + off);
    a2[ks] = *(const s8v*)(A2 + off);
  }

#pragma unroll
  for (int i = 0; i < 8; ++i) {
    int idx = t + i * 512;          // chunk 0..4095
    int mat = idx >> 11;
    int rem = idx & 2047;
    int r = rem >> 4, k = rem & 15;
    int c = k ^ (r & 7);
    const unsigned short* src = (mat ? W2 : W1) + r * 128 + c * 8;
    gload_lds16(src, &Wlds[idx * 8]);
  }
  __syncthreads();

  f32x4 acc[8];
#pragma unroll
  for (int f = 0; f < 8; ++f) acc[f] = (f32x4){0.f, 0.f, 0.f, 0.f};

#pragma unroll
  for (int ks = 0; ks < 4; ++ks) {
#pragma unroll
    for (int f = 0; f < 8; ++f) {
      int ch = swz_chunk(f * 16 + ln, ks * 4 + lg) * 8;
      s8v b1 = *(const s8v*)&Wlds[ch];
      s8v b2 = *(const s8v*)&Wlds[16384 + ch];
      acc[f] = __builtin_amdgcn_mfma_f32_16x16x32_bf16(a1[ks], b1, acc[f], 0, 0, 0);
      acc[f] = __builtin_amdgcn_mfma_f32_16x16x32_bf16(a2[ks], b2, acc[f], 0, 0, 0);
    }
  }

#pragma unroll
  for (int r = 0; r < 4; ++r) {
    int gr = rb + 4 * lg + r;
    float v[8];
#pragma unroll
    for (int f = 0; f < 8; ++f) v[f] = acc[f][r] + bias[f * 16 + ln];
    if (MODE == 0) {
      float ss = 0.f;
#pragma unroll
      for (int f = 0; f < 8; ++f) ss += v[f] * v[f];
      ss += __shfl_xor(ss, 1);
      ss += __shfl_xor(ss, 2);
      ss += __shfl_xor(ss, 4);
      ss += __shfl_xor(ss, 8);
      float sc = 1.0f / fmaxf(sqrtf(ss), 1e-12f);
      if (gr < n) {
        unsigned short* out = (unsigned short*)outv;
#pragma unroll
        for (int f = 0; f < 8; ++f) {
          float o = fmaxf(v[f] * sc, 0.f);
          out[(size_t)f * n16 + (size_t)gr * 16 + ln] = f2bf(o);
        }
      }
    } else {
      if (gr < n) {
        float* out = (float*)outv;
#pragma unroll
        for (int f = 0; f < 8; ++f) out[(size_t)gr * D + f * 16 + ln] = v[f];
      }
    }
  }
}

extern "C" void kernel_launch(void* const* d_in, const int* in_sizes, int n_in,
                              void* d_out, int out_size, void* d_ws, size_t ws_size,
                              hipStream_t stream) {
  const float* x   = (const float*)d_in[0];
  const int*   ei  = (const int*)d_in[1];
  const float* Wp  = (const float*)d_in[2];
  const float* bp  = (const float*)d_in[3];
  const float* Wl  = (const float*)d_in[4];
  const float* bl  = (const float*)d_in[5];
  const float* Wr  = (const float*)d_in[6];
  const float* Wlo = (const float*)d_in[7];
  const float* blo = (const float*)d_in[8];
  const float* Wro = (const float*)d_in[9];

  const int N = in_sizes[0] / D;  // 100000
  const int E = in_sizes[1] / 2;  // 1600000
  const int* srcIdx = ei;
  const int* dstIdx = ei + E;

  const size_t ND = (size_t)N * D;

  unsigned short* xb   = (unsigned short*)d_ws;   // N*D bf16 (slab)
  unsigned short* h    = xb + ND;                 // slab
  unsigned short* aggB = h + ND;                  // slab; aliased: pairs (u32, E) in CSR build
  unsigned short* x2   = aggB + ND;               // slab
  unsigned short* Wb   = x2 + ND;                 // 8*16384 bf16
  int* row_start  = (int*)(Wb + 8 * 16384);       // N+1
  int* bucketCnt  = row_start + N + 1;            // 512
  int* bucketBase = bucketCnt + 512;              // 513
  int* cursor     = bucketBase + 513;             // 512
  int* csr        = cursor + 512;                 // E

  unsigned* pairs = (unsigned*)aggB;

  unsigned short* Wpb0 = Wb;
  unsigned short* Wpb1 = Wb + 16384;
  unsigned short* Wlb0 = Wb + 2 * 16384;
  unsigned short* Wlb1 = Wb + 3 * 16384;
  unsigned short* Wrb0 = Wb + 4 * 16384;
  unsigned short* Wrb1 = Wb + 5 * 16384;
  unsigned short* Wlob = Wb + 6 * 16384;
  unsigned short* Wrob = Wb + 7 * 16384;

  unsigned short* x1 = (unsigned short*)d_out;  // slab scratch until final GEMM

  int gG = (N + 127) / 128;              // 512-thr GEMM blocks (128 rows each)
  int gAg = ((N + 127) / 128) * 8;       // aggregate: chunk*8 + slice
  int KB = (N + 255) / 256;              // buckets
  int gBC = (E + 4095) / 4096;
  int gA  = (E + 16383) / 16384;

  // ---- prep: zero bucketCnt, then weight cvt + bucket count in one dispatch ----
  hipMemsetAsync(bucketCnt, 0, 512 * sizeof(int), stream);
  k_prep<<<128 + gBC, 256, 0, stream>>>(Wp, Wl, Wr, Wlo, Wro, Wb, dstIdx, bucketCnt, E);

  // ---- CSR build (bucketized, packed pairs) ----
  k_bucket_scan<<<1, 512, 0, stream>>>(bucketCnt, bucketBase, cursor, row_start, N, E);
  k_partA<<<gA, 1024, 0, stream>>>(srcIdx, dstIdx, cursor, pairs, E);
  k_partB<<<KB, 256, 0, stream>>>(pairs, bucketBase, row_start, csr, N);

  // ---- layer 0 ----
  k_gemm_proj<1><<<gG, 512, 0, stream>>>(x, Wpb0, bp, h, xb, N);
  k_aggregate<<<gAg, 256, 0, stream>>>(h, aggB, row_start, csr, N);
  k_gemm_dual<0><<<gG, 512, 0, stream>>>(aggB, Wlb0, bl, xb, Wrb0, (void*)x1, N);

  // ---- layer 1 ----
  k_gemm_proj<0><<<gG, 512, 0, stream>>>(x1, Wpb1, bp + D, h, nullptr, N);
  k_aggregate<<<gAg, 256, 0, stream>>>(h, aggB, row_start, csr, N);
  k_gemm_dual<0><<<gG, 512, 0, stream>>>(aggB, Wlb1, bl + D, x1, Wrb1, (void*)x2, N);

  // ---- final layer ----
  k_aggregate<<<gAg, 256, 0, stream>>>(x2, aggB, row_start, csr, N);
  k_gemm_dual<1><<<gG, 512, 0, stream>>>(aggB, Wlob, blo, x2, Wrob, d_out, N);
}

// Round 10
// 323.609 us; speedup vs baseline: 1.2616x; 1.2616x over previous
//
#include <hip/hip_runtime.h>
#include <math.h>

#define D 128

typedef short s8v __attribute__((ext_vector_type(8)));
typedef float f32x4 __attribute__((ext_vector_type(4)));
typedef unsigned short u16x8 __attribute__((ext_vector_type(8)));

__device__ __forceinline__ unsigned short f2bf(float f) {
  union { float f; unsigned u; } c; c.f = f;
  unsigned u = c.u;
  unsigned r = (u + 0x7fffu + ((u >> 16) & 1u)) >> 16;
  return (unsigned short)r;
}

__device__ __forceinline__ void gload_lds16(const void* g, void* l) {
  __builtin_amdgcn_global_load_lds((const __attribute__((address_space(1))) void*)g,
                                   (__attribute__((address_space(3))) void*)l, 16, 0, 0);
}

// ---------------- prep: weight cvt (blocks 0..127) + bucket count (rest) ----------------
__global__ __launch_bounds__(256) void k_prep(const float* __restrict__ Wp,
                                              const float* __restrict__ Wl,
                                              const float* __restrict__ Wr,
                                              const float* __restrict__ Wlo,
                                              const float* __restrict__ Wro,
                                              unsigned short* __restrict__ Wb,
                                              const int* __restrict__ dst,
                                              int* __restrict__ bucketCnt, int E_) {
  int t = threadIdx.x;
  if (blockIdx.x < 128) {
    int i = blockIdx.x * 256 + t;  // float4 units, 0..32767
    const float* s;
    int off;
    if (i < 8192)       { s = Wp;  off = 0; }
    else if (i < 16384) { s = Wl;  off = 8192; }
    else if (i < 24576) { s = Wr;  off = 16384; }
    else if (i < 28672) { s = Wlo; off = 24576; }
    else                { s = Wro; off = 28672; }
    float4 a = ((const float4*)s)[i - off];
    ushort4 o;
    o.x = f2bf(a.x); o.y = f2bf(a.y); o.z = f2bf(a.z); o.w = f2bf(a.w);
    ((ushort4*)Wb)[i] = o;
  } else {
    __shared__ int hist[512];
    hist[t] = 0; hist[t + 256] = 0;
    __syncthreads();
    int base = (blockIdx.x - 128) * 4096;
#pragma unroll
    for (int i = 0; i < 16; i++) {
      int e = base + i * 256 + t;
      if (e < E_) atomicAdd(&hist[dst[e] >> 8], 1);
    }
    __syncthreads();
    int c = hist[t];       if (c) atomicAdd(&bucketCnt[t], c);
    c = hist[t + 256];     if (c) atomicAdd(&bucketCnt[t + 256], c);
  }
}

// single block: exclusive scan of 512 bucket counts
__global__ __launch_bounds__(512) void k_bucket_scan(const int* __restrict__ cnt,
                                                     int* __restrict__ base,
                                                     int* __restrict__ cursor,
                                                     int* __restrict__ row_start,
                                                     int n, int E_) {
  __shared__ int bs[512];
  int t = threadIdx.x;
  int orig = cnt[t];
  bs[t] = orig;
  __syncthreads();
  for (int off = 1; off < 512; off <<= 1) {
    int x = (t >= off) ? bs[t - off] : 0;
    __syncthreads();
    bs[t] += x;
    __syncthreads();
  }
  int ex = bs[t] - orig;
  base[t] = ex;
  cursor[t] = ex;
  if (t == 511) base[512] = bs[511];
  if (t == 0) row_start[n] = E_;   // sentinel
}

// Pass A: bin packed (src<<8|dst&255) into bucket regions. 16384 edges / block.
__global__ __launch_bounds__(1024) void k_partA(const int* __restrict__ src,
                                                const int* __restrict__ dst,
                                                int* __restrict__ cursor,
                                                unsigned* __restrict__ pairs, int E_) {
  __shared__ int hist[512];
  __shared__ int gbase[512];
  int t = threadIdx.x;
  int base = blockIdx.x * 16384;
  if (t < 512) hist[t] = 0;
  __syncthreads();
  unsigned p_[16];
  int k_[16];
#pragma unroll
  for (int i = 0; i < 16; i++) {
    int e = base + i * 1024 + t;
    if (e < E_) {
      int s = src[e], d = dst[e];
      p_[i] = ((unsigned)s << 8) | (unsigned)(d & 255);
      k_[i] = d >> 8;
      atomicAdd(&hist[k_[i]], 1);
    } else {
      k_[i] = -1;
    }
  }
  __syncthreads();
  if (t < 512) {
    int c = hist[t];
    gbase[t] = c ? atomicAdd(&cursor[t], c) : 0;
    hist[t] = 0;
  }
  __syncthreads();
#pragma unroll
  for (int i = 0; i < 16; i++) {
    if (k_[i] >= 0) {
      int r = atomicAdd(&hist[k_[i]], 1);
      pairs[gbase[k_[i]] + r] = p_[i];
    }
  }
}

// LDS fragment address: logical (row r, chunk c) stored at chunk (r*16 + (c ^ (r&7)))
__device__ __forceinline__ int swz_chunk(int r, int c) { return (r << 4) + (c ^ (r & 7)); }

// ---------------- merged: proj layer-0 (blocks < nP) || partB (blocks >= nP) ----------
// proj: 1024 thr = 16 waves, 256 rows/block; A fp32 row-major; writes bf16 A to xb;
// out = relu(x@Wp^T+bp) -> h. partB: CSR finalize for one bucket (1024 threads).
__global__ __launch_bounds__(1024, 4) void k_proj0B(const float* __restrict__ Av,
                                                    const unsigned short* __restrict__ W,
                                                    const float* __restrict__ bias,
                                                    unsigned short* __restrict__ out,
                                                    unsigned short* __restrict__ xb_out,
                                                    const unsigned* __restrict__ pairs,
                                                    const int* __restrict__ bucketBase,
                                                    int* __restrict__ row_start,
                                                    int* __restrict__ csr,
                                                    int n, int nP) {
  __shared__ __align__(16) unsigned short Wlds[128 * 128];
  __shared__ int cnt[256];
  __shared__ int scn[256];
  int t = threadIdx.x;

  if ((int)blockIdx.x < nP) {
    // ---------------- projection ----------------
    int wv = t >> 6, l = t & 63, lg = l >> 4, ln = l & 15;
    int rb = blockIdx.x * 256 + wv * 16;
    int arow = rb + ln;
    if (arow >= n) arow = n - 1;

    s8v a[4];
    const float* Af = Av + (size_t)arow * D + lg * 8;
#pragma unroll
    for (int ks = 0; ks < 4; ++ks) {
      float4 f0 = *(const float4*)(Af + ks * 32);
      float4 f1 = *(const float4*)(Af + ks * 32 + 4);
      s8v av;
      av[0] = (short)f2bf(f0.x); av[1] = (short)f2bf(f0.y);
      av[2] = (short)f2bf(f0.z); av[3] = (short)f2bf(f0.w);
      av[4] = (short)f2bf(f1.x); av[5] = (short)f2bf(f1.y);
      av[6] = (short)f2bf(f1.z); av[7] = (short)f2bf(f1.w);
      a[ks] = av;
      *(s8v*)(xb_out + (size_t)arow * D + lg * 8 + ks * 32) = av;
    }

#pragma unroll
    for (int i = 0; i < 2; ++i) {
      int idx = t + i * 1024;       // chunk 0..2047
      int r = idx >> 4, k = idx & 15;
      int c = k ^ (r & 7);
      gload_lds16(W + r * 128 + c * 8, &Wlds[idx * 8]);
    }
    __syncthreads();

    f32x4 acc[8];
#pragma unroll
    for (int f = 0; f < 8; ++f) acc[f] = (f32x4){0.f, 0.f, 0.f, 0.f};
#pragma unroll
    for (int ks = 0; ks < 4; ++ks) {
#pragma unroll
      for (int f = 0; f < 8; ++f) {
        s8v b = *(const s8v*)&Wlds[swz_chunk(f * 16 + ln, ks * 4 + lg) * 8];
        acc[f] = __builtin_amdgcn_mfma_f32_16x16x32_bf16(a[ks], b, acc[f], 0, 0, 0);
      }
    }

#pragma unroll
    for (int r = 0; r < 4; ++r) {
      int gr = rb + 4 * lg + r;
      if (gr < n) {
#pragma unroll
        for (int f = 0; f < 8; ++f) {
          int c = f * 16 + ln;
          float v = acc[f][r] + bias[c];
          v = fmaxf(v, 0.f);
          out[(size_t)gr * D + c] = f2bf(v);
        }
      }
    }
  } else {
    // ---------------- partB: one bucket, 1024 threads ----------------
    int k = blockIdx.x - nP;
    int node0 = k << 8;
    int pbeg = bucketBase[k], pend = bucketBase[k + 1];
    if (t < 256) cnt[t] = 0;
    __syncthreads();
    for (int p = pbeg + t; p < pend; p += 1024) atomicAdd(&cnt[pairs[p] & 255], 1);
    __syncthreads();
    int c = 0;
    if (t < 256) { c = cnt[t]; scn[t] = c; }
    __syncthreads();
    for (int off = 1; off < 256; off <<= 1) {
      int xv = 0;
      if (t < 256 && t >= off) xv = scn[t - off];
      __syncthreads();
      if (t < 256) scn[t] += xv;
      __syncthreads();
    }
    if (t < 256) {
      int ex = scn[t] - c;
      int node = node0 + t;
      if (node < n) row_start[node] = pbeg + ex;
      cnt[t] = pbeg + ex;   // running cursor per node
    }
    __syncthreads();
    for (int p = pbeg + t; p < pend; p += 1024) {
      unsigned pr = pairs[p];
      int slot = atomicAdd(&cnt[pr & 255], 1);
      csr[slot] = (int)(pr >> 8);
    }
  }
}

// ---------------- mean aggregation: one node per 16-lane group ----------------
// 4 nodes/wave; each group walks its node's full list with a 4-deep pipeline and
// 1-iteration-ahead index prefetch. Row-major h (256 B rows, full-line use).
__global__ __launch_bounds__(256) void k_aggregate(const unsigned short* __restrict__ h,
                                                   unsigned short* __restrict__ agg,
                                                   const int* __restrict__ row_start,
                                                   const int* __restrict__ csr, int n) {
  int node = (blockIdx.x * 256 + threadIdx.x) >> 4;
  int li = threadIdx.x & 15;
  if (node >= n) return;
  int rs0 = row_start[node];
  int dc = row_start[node + 1] - rs0;
  const int* ce = csr + rs0;
  const char* base = (const char*)h + li * 16;   // row r chunk at base + r*256

  float accL[4], accH[4];
#pragma unroll
  for (int q = 0; q < 4; q++) { accL[q] = 0.f; accH[q] = 0.f; }

#define ACCR(v)                                                        \
  {                                                                    \
    unsigned dw[4] = {(v).x, (v).y, (v).z, (v).w};                     \
    _Pragma("unroll") for (int q = 0; q < 4; q++) {                    \
      accL[q] += __uint_as_float(dw[q] << 16);                         \
      accH[q] += __uint_as_float(dw[q] & 0xffff0000u);                 \
    }                                                                  \
  }

  int e = 0;
  bool more = (3 < dc);
  int s0 = 0, s1 = 0, s2 = 0, s3 = 0;
  if (more) { s0 = ce[0]; s1 = ce[1]; s2 = ce[2]; s3 = ce[3]; }
  while (more) {
    uint4 v0 = *(const uint4*)(base + (size_t)s0 * 256);
    uint4 v1 = *(const uint4*)(base + (size_t)s1 * 256);
    uint4 v2 = *(const uint4*)(base + (size_t)s2 * 256);
    uint4 v3 = *(const uint4*)(base + (size_t)s3 * 256);
    e += 4;
    more = (e + 3 < dc);
    if (more) { s0 = ce[e]; s1 = ce[e + 1]; s2 = ce[e + 2]; s3 = ce[e + 3]; }
    ACCR(v0); ACCR(v1); ACCR(v2); ACCR(v3);
  }
  if (e < dc)     { uint4 v = *(const uint4*)(base + (size_t)ce[e] * 256);     ACCR(v); }
  if (e + 1 < dc) { uint4 v = *(const uint4*)(base + (size_t)ce[e + 1] * 256); ACCR(v); }
  if (e + 2 < dc) { uint4 v = *(const uint4*)(base + (size_t)ce[e + 2] * 256); ACCR(v); }
#undef ACCR

  float iv = 1.0f / (float)(dc > 0 ? dc : 1);
  u16x8 o;
#pragma unroll
  for (int q = 0; q < 4; q++) {
    o[2 * q] = f2bf(accL[q] * iv);
    o[2 * q + 1] = f2bf(accH[q] * iv);
  }
  *(u16x8*)(agg + (size_t)node * D + li * 8) = o;
}

// ---------------- projection GEMM (async LDS-staged W): relu(A @ W^T + b) -> bf16 ----
// 512 thr = 8 waves, 128 rows/block. A bf16 row-major.
__global__ __launch_bounds__(512, 4) void k_gemm_proj(const unsigned short* __restrict__ A,
                                                      const unsigned short* __restrict__ W,
                                                      const float* __restrict__ bias,
                                                      unsigned short* __restrict__ out,
                                                      int n) {
  __shared__ __align__(16) unsigned short Wlds[128 * 128];
  int t = threadIdx.x;
  int wv = t >> 6, l = t & 63, lg = l >> 4, ln = l & 15;
  int rb = blockIdx.x * 128 + wv * 16;
  int arow = rb + ln;
  if (arow >= n) arow = n - 1;

  const s8v* Ap = (const s8v*)(A + (size_t)arow * D + lg * 8);
  s8v a[4];
#pragma unroll
  for (int ks = 0; ks < 4; ++ks) a[ks] = Ap[ks * 4];

  // async global->LDS staging, pre-swizzled global source, linear LDS dest
#pragma unroll
  for (int i = 0; i < 4; ++i) {
    int idx = t + i * 512;          // chunk 0..2047
    int r = idx >> 4, k = idx & 15;
    int c = k ^ (r & 7);
    gload_lds16(W + r * 128 + c * 8, &Wlds[idx * 8]);
  }
  __syncthreads();

  f32x4 acc[8];
#pragma unroll
  for (int f = 0; f < 8; ++f) acc[f] = (f32x4){0.f, 0.f, 0.f, 0.f};
#pragma unroll
  for (int ks = 0; ks < 4; ++ks) {
#pragma unroll
    for (int f = 0; f < 8; ++f) {
      s8v b = *(const s8v*)&Wlds[swz_chunk(f * 16 + ln, ks * 4 + lg) * 8];
      acc[f] = __builtin_amdgcn_mfma_f32_16x16x32_bf16(a[ks], b, acc[f], 0, 0, 0);
    }
  }

#pragma unroll
  for (int r = 0; r < 4; ++r) {
    int gr = rb + 4 * lg + r;
    if (gr < n) {
#pragma unroll
      for (int f = 0; f < 8; ++f) {
        int c = f * 16 + ln;
        float v = acc[f][r] + bias[c];
        v = fmaxf(v, 0.f);
        out[(size_t)gr * D + c] = f2bf(v);
      }
    }
  }
}

// ---------------- dual GEMM (async LDS-staged W1+W2): A1@W1^T + b + A2@W2^T ----------
// MODE 0: L2-normalize rows then relu, store bf16. MODE 1: store fp32.
template <int MODE>
__global__ __launch_bounds__(512, 4) void k_gemm_dual(const unsigned short* __restrict__ A1,
                                                      const unsigned short* __restrict__ W1,
                                                      const float* __restrict__ bias,
                                                      const unsigned short* __restrict__ A2,
                                                      const unsigned short* __restrict__ W2,
                                                      void* __restrict__ outv, int n) {
  __shared__ __align__(16) unsigned short Wlds[2 * 128 * 128];
  int t = threadIdx.x;
  int wv = t >> 6, l = t & 63, lg = l >> 4, ln = l & 15;
  int rb = blockIdx.x * 128 + wv * 16;
  int arow = rb + ln;
  if (arow >= n) arow = n - 1;
  const s8v* A1p = (const s8v*)(A1 + (size_t)arow * D + lg * 8);
  const s8v* A2p = (const s8v*)(A2 + (size_t)arow * D + lg * 8);
  s8v a1[4], a2[4];
#pragma unroll
  for (int ks = 0; ks < 4; ++ks) { a1[ks] = A1p[ks * 4]; a2[ks] = A2p[ks * 4]; }

#pragma unroll
  for (int i = 0; i < 8; ++i) {
    int idx = t + i * 512;          // chunk 0..4095
    int mat = idx >> 11;
    int rem = idx & 2047;
    int r = rem >> 4, k = rem & 15;
    int c = k ^ (r & 7);
    const unsigned short* src = (mat ? W2 : W1) + r * 128 + c * 8;
    gload_lds16(src, &Wlds[idx * 8]);
  }
  __syncthreads();

  f32x4 acc[8];
#pragma unroll
  for (int f = 0; f < 8; ++f) acc[f] = (f32x4){0.f, 0.f, 0.f, 0.f};

#pragma unroll
  for (int ks = 0; ks < 4; ++ks) {
#pragma unroll
    for (int f = 0; f < 8; ++f) {
      int ch = swz_chunk(f * 16 + ln, ks * 4 + lg) * 8;
      s8v b1 = *(const s8v*)&Wlds[ch];
      s8v b2 = *(const s8v*)&Wlds[16384 + ch];
      acc[f] = __builtin_amdgcn_mfma_f32_16x16x32_bf16(a1[ks], b1, acc[f], 0, 0, 0);
      acc[f] = __builtin_amdgcn_mfma_f32_16x16x32_bf16(a2[ks], b2, acc[f], 0, 0, 0);
    }
  }

#pragma unroll
  for (int r = 0; r < 4; ++r) {
    int gr = rb + 4 * lg + r;
    float v[8];
#pragma unroll
    for (int f = 0; f < 8; ++f) v[f] = acc[f][r] + bias[f * 16 + ln];
    if (MODE == 0) {
      float ss = 0.f;
#pragma unroll
      for (int f = 0; f < 8; ++f) ss += v[f] * v[f];
      ss += __shfl_xor(ss, 1);
      ss += __shfl_xor(ss, 2);
      ss += __shfl_xor(ss, 4);
      ss += __shfl_xor(ss, 8);
      float sc = 1.0f / fmaxf(sqrtf(ss), 1e-12f);
      if (gr < n) {
        unsigned short* out = (unsigned short*)outv;
#pragma unroll
        for (int f = 0; f < 8; ++f) {
          float o = fmaxf(v[f] * sc, 0.f);
          out[(size_t)gr * D + f * 16 + ln] = f2bf(o);
        }
      }
    } else {
      if (gr < n) {
        float* out = (float*)outv;
#pragma unroll
        for (int f = 0; f < 8; ++f) out[(size_t)gr * D + f * 16 + ln] = v[f];
      }
    }
  }
}

extern "C" void kernel_launch(void* const* d_in, const int* in_sizes, int n_in,
                              void* d_out, int out_size, void* d_ws, size_t ws_size,
                              hipStream_t stream) {
  const float* x   = (const float*)d_in[0];
  const int*   ei  = (const int*)d_in[1];
  const float* Wp  = (const float*)d_in[2];
  const float* bp  = (const float*)d_in[3];
  const float* Wl  = (const float*)d_in[4];
  const float* bl  = (const float*)d_in[5];
  const float* Wr  = (const float*)d_in[6];
  const float* Wlo = (const float*)d_in[7];
  const float* blo = (const float*)d_in[8];
  const float* Wro = (const float*)d_in[9];

  const int N = in_sizes[0] / D;  // 100000
  const int E = in_sizes[1] / 2;  // 1600000
  const int* srcIdx = ei;
  const int* dstIdx = ei + E;

  const size_t ND = (size_t)N * D;

  unsigned short* xb   = (unsigned short*)d_ws;   // N*D bf16
  unsigned short* h    = xb + ND;
  unsigned short* aggB = h + ND;                  // aliased: pairs (u32, E) during CSR build
  unsigned short* x2   = aggB + ND;
  unsigned short* Wb   = x2 + ND;                 // 8*16384 bf16
  int* row_start  = (int*)(Wb + 8 * 16384);       // N+1
  int* bucketCnt  = row_start + N + 1;            // 512
  int* bucketBase = bucketCnt + 512;              // 513
  int* cursor     = bucketBase + 513;             // 512
  int* csr        = cursor + 512;                 // E

  unsigned* pairs = (unsigned*)aggB;

  unsigned short* Wpb0 = Wb;
  unsigned short* Wpb1 = Wb + 16384;
  unsigned short* Wlb0 = Wb + 2 * 16384;
  unsigned short* Wlb1 = Wb + 3 * 16384;
  unsigned short* Wrb0 = Wb + 4 * 16384;
  unsigned short* Wrb1 = Wb + 5 * 16384;
  unsigned short* Wlob = Wb + 6 * 16384;
  unsigned short* Wrob = Wb + 7 * 16384;

  unsigned short* x1 = (unsigned short*)d_out;  // scratch until final GEMM

  int gG  = (N + 127) / 128;           // 512-thr GEMM blocks (128 rows each)
  int gP  = (N + 255) / 256;           // 1024-thr proj-L0 blocks (256 rows each)
  int gAg = (N * 16 + 255) / 256;      // aggregate: 16 threads per node
  int KB  = (N + 255) / 256;           // buckets
  int gBC = (E + 4095) / 4096;
  int gA  = (E + 16383) / 16384;

  // ---- prep: zero bucketCnt, then weight cvt + bucket count in one dispatch ----
  hipMemsetAsync(bucketCnt, 0, 512 * sizeof(int), stream);
  k_prep<<<128 + gBC, 256, 0, stream>>>(Wp, Wl, Wr, Wlo, Wro, Wb, dstIdx, bucketCnt, E);

  // ---- CSR build (bucketized, packed pairs) ----
  k_bucket_scan<<<1, 512, 0, stream>>>(bucketCnt, bucketBase, cursor, row_start, N, E);
  k_partA<<<gA, 1024, 0, stream>>>(srcIdx, dstIdx, cursor, pairs, E);

  // ---- layer 0 projection || CSR finalize (independent, merged dispatch) ----
  k_proj0B<<<gP + KB, 1024, 0, stream>>>(x, Wpb0, bp, h, xb,
                                         pairs, bucketBase, row_start, csr, N, gP);

  // ---- layer 0 ----
  k_aggregate<<<gAg, 256, 0, stream>>>(h, aggB, row_start, csr, N);
  k_gemm_dual<0><<<gG, 512, 0, stream>>>(aggB, Wlb0, bl, xb, Wrb0, (void*)x1, N);

  // ---- layer 1 ----
  k_gemm_proj<<<gG, 512, 0, stream>>>(x1, Wpb1, bp + D, h, N);
  k_aggregate<<<gAg, 256, 0, stream>>>(h, aggB, row_start, csr, N);
  k_gemm_dual<0><<<gG, 512, 0, stream>>>(aggB, Wlb1, bl + D, x1, Wrb1, (void*)x2, N);

  // ---- final layer ----
  k_aggregate<<<gAg, 256, 0, stream>>>(x2, aggB, row_start, csr, N);
  k_gemm_dual<1><<<gG, 512, 0, stream>>>(aggB, Wlob, blo, x2, Wrob, d_out, N);
}